// Round 1
// baseline (98.259 us; speedup 1.0000x reference)
//
#include <hip/hip_runtime.h>
#include <math.h>

#define BLOCK 256
#define CHUNK 16   // l-values per thread; L=4096 -> one y-block

// out[h,l] = 2 * Re( sum_n C'_{hn} * exp(dtA_{hn})^l )
// Thread t of block h handles l = base + t + 256*j (coalesced stores),
// stepping s *= w^256 (geometric recurrence, 16 steps max per thread).
__global__ __launch_bounds__(BLOCK) void s4_vandermonde(
    const float* __restrict__ log_dt,
    const float* __restrict__ C_re,
    const float* __restrict__ C_im,
    const float* __restrict__ log_A_re,
    const float* __restrict__ A_im,
    float* __restrict__ out,
    int n, int L)
{
    const int h   = blockIdx.x;
    const int base = blockIdx.y * (BLOCK * CHUNK);
    const int tid = threadIdx.x;

    extern __shared__ float smem[];
    float* s_x  = smem;         // Re(dtA)
    float* s_y  = s_x  + n;     // Im(dtA)
    float* s_cr = s_y  + n;     // Re(C')
    float* s_ci = s_cr + n;     // Im(C')
    float* s_wr = s_ci + n;     // Re(w^BLOCK)
    float* s_wi = s_wr + n;     // Im(w^BLOCK)

    // Per-(h,n) precompute by first n threads.
    for (int i = tid; i < n; i += BLOCK) {
        const float dt  = __expf(log_dt[h]);
        const float Are = -__expf(log_A_re[(size_t)h * n + i]);
        const float Aim = A_im[(size_t)h * n + i];
        const float x = Are * dt;           // always < 0 (decay)
        const float y = Aim * dt;

        // w = exp(dtA) = e^x (cos y + i sin y)
        float ex = __expf(x), sy, cy;
        __sincosf(y, &sy, &cy);
        const float er = ex * cy, ei = ex * sy;

        // C' = C * (w - 1) / A   (|A|^2 >= Aim^2 = 1, no div hazard)
        const float numr = er - 1.0f, numi = ei;
        const float inv  = 1.0f / (Are * Are + Aim * Aim);
        const float dr = (numr * Are + numi * Aim) * inv;
        const float di = (numi * Are - numr * Aim) * inv;
        const float Cr = C_re[(size_t)h * n + i];
        const float Ci = C_im[(size_t)h * n + i];
        s_cr[i] = Cr * dr - Ci * di;
        s_ci[i] = Cr * di + Ci * dr;
        s_x[i] = x;
        s_y[i] = y;

        // w_step = w^BLOCK = exp(dtA * 256)
        float exs = __expf(x * (float)BLOCK), ss, cs;
        __sincosf(y * (float)BLOCK, &ss, &cs);
        s_wr[i] = exs * cs;
        s_wi[i] = exs * ss;
    }
    __syncthreads();

    float acc[CHUNK];
#pragma unroll
    for (int j = 0; j < CHUNK; ++j) acc[j] = 0.0f;

    const float fl = (float)(base + tid);   // starting l for this thread

    for (int i = 0; i < n; ++i) {
        const float x = s_x[i], y = s_y[i];
        // s = C' * w^l0  (direct eval of starting point)
        float e0 = __expf(x * fl), s0, c0;
        __sincosf(y * fl, &s0, &c0);
        const float cr = s_cr[i], ci = s_ci[i];
        float sr = e0 * (cr * c0 - ci * s0);
        float si = e0 * (cr * s0 + ci * c0);
        const float wr = s_wr[i], wi = s_wi[i];
#pragma unroll
        for (int j = 0; j < CHUNK; ++j) {
            acc[j] += sr;
            const float tr = sr * wr - si * wi;
            const float ti = sr * wi + si * wr;
            sr = tr;
            si = ti;
        }
    }

    float* o = out + (size_t)h * L + base + tid;
#pragma unroll
    for (int j = 0; j < CHUNK; ++j) {
        const int l = base + tid + j * BLOCK;
        if (l < L) o[(size_t)j * BLOCK] = 2.0f * acc[j];
    }
}

extern "C" void kernel_launch(void* const* d_in, const int* in_sizes, int n_in,
                              void* d_out, int out_size, void* d_ws, size_t ws_size,
                              hipStream_t stream) {
    const float* log_dt   = (const float*)d_in[0];
    const float* C_re     = (const float*)d_in[1];
    const float* C_im     = (const float*)d_in[2];
    const float* log_A_re = (const float*)d_in[3];
    const float* A_im     = (const float*)d_in[4];
    float* out = (float*)d_out;

    const int H = in_sizes[0];          // 1024
    const int n = in_sizes[1] / H;      // 32
    const int L = out_size / H;         // 4096 (avoid device read of d_in[5])

    const int lchunks = (L + BLOCK * CHUNK - 1) / (BLOCK * CHUNK);
    dim3 grid(H, lchunks);
    const size_t lds = (size_t)6 * n * sizeof(float);
    s4_vandermonde<<<grid, BLOCK, lds, stream>>>(
        log_dt, C_re, C_im, log_A_re, A_im, out, n, L);
}

// Round 2
// 80.218 us; speedup vs baseline: 1.2249x; 1.2249x over previous
//
#include <hip/hip_runtime.h>
#include <math.h>

#define BLOCK 128
#define CHUNK 32   // l-values per thread; BLOCK*CHUNK = 4096 = L -> one y-block

typedef float f32x2 __attribute__((ext_vector_type(2)));

// out[h,l] = 2 * Re( sum_n C'_{hn} * exp(dtA_{hn})^l )
//
// Thread t of block h handles l = base + t + BLOCK*j (coalesced stores).
// Instead of a complex geometric recurrence (5 ops/term), use the real
// second-order recurrence satisfied by r_j = Re(C' w^{l0 + j*BLOCK}):
//     r_{j+1} = 2Re(W) r_j - |W|^2 r_{j-1},   W = w^BLOCK
// (roots W, conj(W), |W|<1 -> stable). 2 fma + 1 add per term, and modes
// are processed in pairs via packed f32x2 -> v_pk_fma_f32 on gfx950.
__global__ __launch_bounds__(BLOCK) void s4_vandermonde(
    const float* __restrict__ log_dt,
    const float* __restrict__ C_re,
    const float* __restrict__ C_im,
    const float* __restrict__ log_A_re,
    const float* __restrict__ A_im,
    float* __restrict__ out,
    int n, int L)
{
    const int h    = blockIdx.x;
    const int base = blockIdx.y * (BLOCK * CHUNK);
    const int tid  = threadIdx.x;

    extern __shared__ float smem[];
    float* s_x  = smem;         // Re(dtA)
    float* s_y  = s_x  + n;     // Im(dtA)
    float* s_cr = s_y  + n;     // Re(C')
    float* s_ci = s_cr + n;     // Im(C')
    float* s_wr = s_ci + n;     // Re(W)   (W = w^BLOCK)
    float* s_wi = s_wr + n;     // Im(W)
    float* s_a  = s_wi + n;     // 2*Re(W)
    float* s_nb = s_a  + n;     // -|W|^2

    // Per-(h,n) precompute by first n threads.
    for (int i = tid; i < n; i += BLOCK) {
        const float dt  = __expf(log_dt[h]);
        const float Are = -__expf(log_A_re[(size_t)h * n + i]);
        const float Aim = A_im[(size_t)h * n + i];
        const float x = Are * dt;           // always < 0 (decay)
        const float y = Aim * dt;

        // w = exp(dtA)
        float ex = __expf(x), sy, cy;
        __sincosf(y, &sy, &cy);
        const float er = ex * cy, ei = ex * sy;

        // C' = C * (w - 1) / A   (|A|^2 >= Aim^2 = 1, no div hazard)
        const float numr = er - 1.0f, numi = ei;
        const float inv  = 1.0f / (Are * Are + Aim * Aim);
        const float dr = (numr * Are + numi * Aim) * inv;
        const float di = (numi * Are - numr * Aim) * inv;
        const float Cr = C_re[(size_t)h * n + i];
        const float Ci = C_im[(size_t)h * n + i];
        s_cr[i] = Cr * dr - Ci * di;
        s_ci[i] = Cr * di + Ci * dr;
        s_x[i] = x;
        s_y[i] = y;

        // W = w^BLOCK = exp(dtA * BLOCK)
        float exs = __expf(x * (float)BLOCK), ss, cs;
        __sincosf(y * (float)BLOCK, &ss, &cs);
        const float Wr = exs * cs, Wi = exs * ss;
        s_wr[i] = Wr;
        s_wi[i] = Wi;
        s_a[i]  = 2.0f * Wr;            // 2 Re(W)
        s_nb[i] = -(exs * exs);         // -|W|^2 = -exp(2*BLOCK*x)
    }
    __syncthreads();

    f32x2 acc[CHUNK];
#pragma unroll
    for (int j = 0; j < CHUNK; ++j) acc[j] = (f32x2)(0.0f);

    const float fl = (float)(base + tid);   // starting l for this thread
    const int npair = n >> 1;

    for (int p = 0; p < npair; ++p) {
        const int i0 = 2 * p, i1 = 2 * p + 1;
        f32x2 rp, rc;
        // init mode i0
        {
            const float x = s_x[i0], y = s_y[i0];
            float e0 = __expf(x * fl), s0, c0;
            __sincosf(y * fl, &s0, &c0);
            const float cr = s_cr[i0], ci = s_ci[i0];
            const float sr = e0 * (cr * c0 - ci * s0);
            const float si = e0 * (cr * s0 + ci * c0);
            rp.x = sr;
            rc.x = sr * s_wr[i0] - si * s_wi[i0];   // Re(s*W)
        }
        // init mode i1
        {
            const float x = s_x[i1], y = s_y[i1];
            float e0 = __expf(x * fl), s0, c0;
            __sincosf(y * fl, &s0, &c0);
            const float cr = s_cr[i1], ci = s_ci[i1];
            const float sr = e0 * (cr * c0 - ci * s0);
            const float si = e0 * (cr * s0 + ci * c0);
            rp.y = sr;
            rc.y = sr * s_wr[i1] - si * s_wi[i1];
        }
        const f32x2 a01  = { s_a[i0],  s_a[i1] };
        const f32x2 nb01 = { s_nb[i0], s_nb[i1] };

        acc[0] += rp;
        acc[1] += rc;
#pragma unroll
        for (int j = 2; j < CHUNK; ++j) {
            const f32x2 rn = __builtin_elementwise_fma(a01, rc, nb01 * rp);
            acc[j] += rn;
            rp = rc;
            rc = rn;
        }
    }
    // odd-n tail (n=32 in practice; keep for robustness)
    if (n & 1) {
        const int i = n - 1;
        const float x = s_x[i], y = s_y[i];
        float e0 = __expf(x * fl), s0, c0;
        __sincosf(y * fl, &s0, &c0);
        const float cr = s_cr[i], ci = s_ci[i];
        const float sr = e0 * (cr * c0 - ci * s0);
        const float si = e0 * (cr * s0 + ci * c0);
        float rp = sr;
        float rc = sr * s_wr[i] - si * s_wi[i];
        const float a = s_a[i], nb = s_nb[i];
        acc[0].x += rp;
        acc[1].x += rc;
#pragma unroll
        for (int j = 2; j < CHUNK; ++j) {
            const float rn = fmaf(a, rc, nb * rp);
            acc[j].x += rn;
            rp = rc;
            rc = rn;
        }
    }

    float* o = out + (size_t)h * L + base + tid;
#pragma unroll
    for (int j = 0; j < CHUNK; ++j) {
        const int l = base + tid + j * BLOCK;
        if (l < L) o[(size_t)j * BLOCK] = 2.0f * (acc[j].x + acc[j].y);
    }
}

extern "C" void kernel_launch(void* const* d_in, const int* in_sizes, int n_in,
                              void* d_out, int out_size, void* d_ws, size_t ws_size,
                              hipStream_t stream) {
    const float* log_dt   = (const float*)d_in[0];
    const float* C_re     = (const float*)d_in[1];
    const float* C_im     = (const float*)d_in[2];
    const float* log_A_re = (const float*)d_in[3];
    const float* A_im     = (const float*)d_in[4];
    float* out = (float*)d_out;

    const int H = in_sizes[0];          // 1024
    const int n = in_sizes[1] / H;      // 32
    const int L = out_size / H;         // 4096 (avoid device read of d_in[5])

    const int lchunks = (L + BLOCK * CHUNK - 1) / (BLOCK * CHUNK);
    dim3 grid(H, lchunks);
    const size_t lds = (size_t)8 * n * sizeof(float);
    s4_vandermonde<<<grid, BLOCK, lds, stream>>>(
        log_dt, C_re, C_im, log_A_re, A_im, out, n, L);
}